// Round 1
// baseline (320.291 us; speedup 1.0000x reference)
//
#include <hip/hip_runtime.h>
#include <stdint.h>

#define N 8192
#define C 128

typedef float f32x4 __attribute__((ext_vector_type(4)));
typedef short bf16x8 __attribute__((ext_vector_type(8)));

__device__ __forceinline__ float wred(float v){
#pragma unroll
  for(int o=32;o;o>>=1) v += __shfl_xor(v,o);
  return v;
}
__device__ __forceinline__ unsigned short f2bf(float x){
  union{float f; unsigned u;} c; c.f = x;
  unsigned u = c.u;
  u += 0x7fffu + ((u>>16)&1u);
  return (unsigned short)(u>>16);
}
__device__ __forceinline__ float lrelu(float z){ return z>0.f ? z : 0.01f*z; }

// ---------------- K1: x_norm = LN(x) ----------------
__global__ void k_ln1(const float* __restrict__ x, const float* __restrict__ g,
                      const float* __restrict__ b, float* __restrict__ xn){
  int l = threadIdx.x & 63, w = threadIdx.x >> 6;
  int i = blockIdx.x*4 + w;
  const float2 xv = *(const float2*)(x + (size_t)i*C + l*2);
  float mu = wred(xv.x + xv.y) * (1.f/C);
  float dx = xv.x - mu, dy = xv.y - mu;
  float var = wred(dx*dx + dy*dy) * (1.f/C);
  float rs = rsqrtf(var + 1e-5f);
  const float2 gv = *(const float2*)(g + l*2);
  const float2 bv = *(const float2*)(b + l*2);
  float2 o; o.x = dx*rs*gv.x + bv.x; o.y = dy*rs*gv.y + bv.y;
  *(float2*)(xn + (size_t)i*C + l*2) = o;
}

// ---------------- K2: h[k] = xn @ W0[k] (f32) ----------------
// grid (N/32, 2), block 256
__global__ void k_gemm_xw(const float* __restrict__ xn, const float* __restrict__ W0,
                          float* __restrict__ h){
  __shared__ __align__(16) float ws[C*C];
  __shared__ __align__(16) float xs[32*C];
  int t = threadIdx.x, k = blockIdx.y, r0 = blockIdx.x*32;
  const float4* wsrc = (const float4*)(W0 + (size_t)k*C*C);
  float4* wdst = (float4*)ws;
#pragma unroll
  for(int r=0;r<16;r++) wdst[t + r*256] = wsrc[t + r*256];
  const float4* xsrc = (const float4*)(xn + (size_t)r0*C);
  float4* xdst = (float4*)xs;
#pragma unroll
  for(int r=0;r<4;r++) xdst[t + r*256] = xsrc[t + r*256];
  __syncthreads();
  int cq = t & 31, rq = t >> 5;
  float4 acc[4] = {};
  const float4* ws4 = (const float4*)ws;
#pragma unroll 4
  for(int kk=0; kk<C; ++kk){
    float4 wv = ws4[kk*32 + cq];
#pragma unroll
    for(int r=0;r<4;r++){
      float xv = xs[(rq*4+r)*C + kk];
      acc[r].x += xv*wv.x; acc[r].y += xv*wv.y; acc[r].z += xv*wv.z; acc[r].w += xv*wv.w;
    }
  }
#pragma unroll
  for(int r=0;r<4;r++)
    *(float4*)(h + (size_t)k*N*C + (size_t)(r0+rq*4+r)*C + cq*4) = acc[r];
}

// ---------------- K2b: hB = fragment-ordered bf16 copy of h ----------------
// layout: hB[((k*256 + jblk)*8 + cb)*512 + lane*8 + t] =
//         bf16(h[k][jblk*32 + (lane>>4)*8 + t][cb*16 + (lane&15)])
__global__ void k_hB(const float* __restrict__ h, unsigned short* __restrict__ hB){
  int id = blockIdx.x*256 + threadIdx.x;
  int t = id & 7, lane = (id>>3)&63, cb = (id>>9)&7, jblk = (id>>12)&255, k = (id>>20)&1;
  int row = jblk*32 + ((lane>>4)<<3) + t;
  int col = cb*16 + (lane&15);
  hB[id] = f2bf(h[(size_t)k*N*C + (size_t)row*C + col]);
}

// ---------------- K3: hl/hr projections ----------------
__global__ void k_hlr(const float* __restrict__ h, const float* __restrict__ a,
                      float* __restrict__ hl, float* __restrict__ hr){
  int l = threadIdx.x & 63, w = threadIdx.x >> 6;
  int wid = blockIdx.x*4 + w;
  int k = wid >> 13, i = wid & (N-1);
  const float2 hv = *(const float2*)(h + (size_t)k*N*C + (size_t)i*C + l*2);
  const float2 al = *(const float2*)(a + k*2*C + l*2);
  const float2 ar = *(const float2*)(a + k*2*C + C + l*2);
  float sl = wred(hv.x*al.x + hv.y*al.y);
  float sr = wred(hv.x*ar.x + hv.y*ar.y);
  if(l==0){ hl[k*N+i] = sl; hr[k*N+i] = sr; }
}

// ---------------- K4: softmax denominators (pass 1 over adj) ----------------
// block 512 (8 rows/block), grid N/8
__global__ void k_denom(const float* __restrict__ adj, const float* __restrict__ hl,
                        const float* __restrict__ hr, float* __restrict__ invd){
  __shared__ __align__(16) float hrs[2*N];
  int t = threadIdx.x;
  const float4* hr4 = (const float4*)hr;
  float4* hrs4 = (float4*)hrs;
#pragma unroll
  for(int r=0;r<8;r++){ int f = t + r*512; hrs4[f] = hr4[f]; }
  __syncthreads();
  int l = t & 63, w = t >> 6;
  int i = blockIdx.x*8 + w;
  float hl0 = hl[i], hl1 = hl[N+i];
  const float4* arow = (const float4*)(adj + (size_t)i*N);
  float s0 = 0.f, s1 = 0.f;
  for(int it=0; it<N/256; ++it){
    int j0 = it*256 + l*4;
    float4 av = arow[it*64 + l];
    float4 h0 = *(const float4*)&hrs[j0];
    float4 h1 = *(const float4*)&hrs[N + j0];
    float avs[4] = {av.x,av.y,av.z,av.w};
    float h0s[4] = {h0.x,h0.y,h0.z,h0.w};
    float h1s[4] = {h1.x,h1.y,h1.z,h1.w};
#pragma unroll
    for(int tt=0; tt<4; ++tt){
      bool m = (avs[tt] > 0.f) || (j0+tt == i);
      float e0 = __expf(lrelu(hl0 + h0s[tt]));
      float e1 = __expf(lrelu(hl1 + h1s[tt]));
      s0 += m ? e0 : 0.f;
      s1 += m ? e1 : 0.f;
    }
  }
  s0 = wred(s0); s1 = wred(s1);
  if(l==0){ invd[i] = 1.f/s0; invd[N+i] = 1.f/s1; }
}

// ---------------- K5: main fused pass ----------------
// grid (128 rowtiles, 8 j-chunks), block 256 (4 waves x 16 rows, JSPAN=1024)
__global__ void k_main(const float* __restrict__ adj, const float* __restrict__ hl,
                       const float* __restrict__ hr, const float* __restrict__ invd,
                       const unsigned short* __restrict__ hB,
                       float* __restrict__ agg, float* __restrict__ pvp){
  __shared__ __align__(16) float hrs[2*1024];
  __shared__ __align__(16) unsigned short hBs[2*8*64*8]; // 16 KiB
  int t = threadIdx.x, l = t & 63, w = t >> 6;
  int r0 = blockIdx.x*64, ch = blockIdx.y;
  int i = r0 + w*16 + (l & 15);
  // stage hr slice for this chunk
#pragma unroll
  for(int r=0;r<8;r++){
    int f = t + r*256;
    int k = f >> 10, jj = f & 1023;
    hrs[f] = hr[k*N + ch*1024 + jj];
  }
  float hl0 = hl[i], hl1 = hl[N+i];
  float id0 = invd[i], id1 = invd[N+i];
  const float* arow = adj + (size_t)i*N;
  float* grow = agg + (size_t)i*N;
  f32x4 acc[2][8] = {};
  const uint4* hBu = (const uint4*)hB;
  uint4* dst = (uint4*)hBs;
  __syncthreads();
  for(int js=0; js<32; ++js){
    int jblk = ch*32 + js;
#pragma unroll
    for(int r=0;r<4;r++){
      int f = t + r*256;
      int k = f >> 9, rem = f & 511;
      dst[f] = hBu[k*131072 + jblk*512 + rem];
    }
    __syncthreads();
    int jb = jblk*32 + ((l>>4)<<3);
    int jl = jb - ch*1024;
    float4 a0 = *(const float4*)(arow + jb);
    float4 a1 = *(const float4*)(arow + jb + 4);
    float4 r00 = *(const float4*)&hrs[jl];
    float4 r01 = *(const float4*)&hrs[jl + 4];
    float4 r10 = *(const float4*)&hrs[1024 + jl];
    float4 r11 = *(const float4*)&hrs[1024 + jl + 4];
    float av[8]  = {a0.x,a0.y,a0.z,a0.w, a1.x,a1.y,a1.z,a1.w};
    float h0v[8] = {r00.x,r00.y,r00.z,r00.w, r01.x,r01.y,r01.z,r01.w};
    float h1v[8] = {r10.x,r10.y,r10.z,r10.w, r11.x,r11.y,r11.z,r11.w};
    float p0[8], p1[8];
#pragma unroll
    for(int tt=0; tt<8; ++tt){
      bool m = (av[tt] > 0.f) || (jb+tt == i);
      float e0 = __expf(lrelu(hl0 + h0v[tt]));
      float e1 = __expf(lrelu(hl1 + h1v[tt]));
      p0[tt] = m ? e0 : 0.f;
      p1[tt] = m ? e1 : 0.f;
    }
    float4 g0, g1;
    g0.x = (p0[0]*id0 + p1[0]*id1)*0.5f;
    g0.y = (p0[1]*id0 + p1[1]*id1)*0.5f;
    g0.z = (p0[2]*id0 + p1[2]*id1)*0.5f;
    g0.w = (p0[3]*id0 + p1[3]*id1)*0.5f;
    g1.x = (p0[4]*id0 + p1[4]*id1)*0.5f;
    g1.y = (p0[5]*id0 + p1[5]*id1)*0.5f;
    g1.z = (p0[6]*id0 + p1[6]*id1)*0.5f;
    g1.w = (p0[7]*id0 + p1[7]*id1)*0.5f;
    *(float4*)(grow + jb) = g0;
    *(float4*)(grow + jb + 4) = g1;
    bf16x8 fa0, fa1;
#pragma unroll
    for(int tt=0; tt<8; ++tt){
      fa0[tt] = (short)f2bf(p0[tt]);
      fa1[tt] = (short)f2bf(p1[tt]);
    }
#pragma unroll
    for(int cb=0; cb<8; ++cb){
      bf16x8 b0 = *(const bf16x8*)&hBs[(cb*64 + l)*8];
      bf16x8 b1 = *(const bf16x8*)&hBs[4096 + (cb*64 + l)*8];
      acc[0][cb] = __builtin_amdgcn_mfma_f32_16x16x32_bf16(fa0, b0, acc[0][cb], 0, 0, 0);
      acc[1][cb] = __builtin_amdgcn_mfma_f32_16x16x32_bf16(fa1, b1, acc[1][cb], 0, 0, 0);
    }
    __syncthreads();
  }
  // write PV partials: D layout row=(l>>4)*4+r, col=lane&15
#pragma unroll
  for(int k=0;k<2;k++)
#pragma unroll
    for(int cb=0;cb<8;cb++)
#pragma unroll
      for(int r=0;r<4;r++){
        int ig = r0 + w*16 + ((l>>4)<<2) + r;
        int c = cb*16 + (l & 15);
        pvp[(size_t)((ch*2 + k)*N + ig)*C + c] = acc[k][cb][r];
      }
}

// ---------------- K6: reduce partials, +x, LN2 -> tmp ----------------
__global__ void k_reduce_ln(const float* __restrict__ pvp, const float* __restrict__ invd,
                            const float* __restrict__ x, const float* __restrict__ g2,
                            const float* __restrict__ b2, float* __restrict__ tmp){
  int l = threadIdx.x & 63, w = threadIdx.x >> 6;
  int wid = blockIdx.x*4 + w;
  int k = wid >> 13, i = wid & (N-1);
  float s0 = 0.f, s1 = 0.f;
#pragma unroll
  for(int ch=0; ch<8; ++ch){
    const float2 v = *(const float2*)(pvp + (size_t)((ch*2+k)*N + i)*C + l*2);
    s0 += v.x; s1 += v.y;
  }
  float idv = invd[k*N + i];
  const float2 xv = *(const float2*)(x + (size_t)i*C + l*2);
  float a0 = s0*idv + xv.x, a1 = s1*idv + xv.y;
  float mu = wred(a0 + a1) * (1.f/C);
  float d0 = a0 - mu, d1 = a1 - mu;
  float var = wred(d0*d0 + d1*d1) * (1.f/C);
  float rs = rsqrtf(var + 1e-5f);
  const float2 gv = *(const float2*)(g2 + l*2);
  const float2 bv = *(const float2*)(b2 + l*2);
  float2 o; o.x = d0*rs*gv.x + bv.x; o.y = d1*rs*gv.y + bv.y;
  *(float2*)(tmp + (size_t)k*N*C + (size_t)i*C + l*2) = o;
}

// ---------------- K7: h_next = sum_k elu(tmp_k @ W1[k]) / 2 ----------------
__global__ void k_out(const float* __restrict__ tmp, const float* __restrict__ W1,
                      float* __restrict__ out){
  __shared__ __align__(16) float ws[C*C];
  __shared__ __align__(16) float xs[32*C];
  int t = threadIdx.x, r0 = blockIdx.x*32;
  int cq = t & 31, rq = t >> 5;
  float oacc[4][4] = {};
  for(int k=0;k<2;k++){
    __syncthreads();
    const float4* wsrc = (const float4*)(W1 + (size_t)k*C*C);
    float4* wdst = (float4*)ws;
#pragma unroll
    for(int r=0;r<16;r++) wdst[t + r*256] = wsrc[t + r*256];
    const float4* xsrc = (const float4*)(tmp + (size_t)k*N*C + (size_t)r0*C);
    float4* xdst = (float4*)xs;
#pragma unroll
    for(int r=0;r<4;r++) xdst[t + r*256] = xsrc[t + r*256];
    __syncthreads();
    float4 acc[4] = {};
    const float4* ws4 = (const float4*)ws;
#pragma unroll 4
    for(int kk=0; kk<C; ++kk){
      float4 wv = ws4[kk*32 + cq];
#pragma unroll
      for(int r=0;r<4;r++){
        float xv = xs[(rq*4+r)*C + kk];
        acc[r].x += xv*wv.x; acc[r].y += xv*wv.y; acc[r].z += xv*wv.z; acc[r].w += xv*wv.w;
      }
    }
#pragma unroll
    for(int r=0;r<4;r++){
      float* ac = (float*)&acc[r];
#pragma unroll
      for(int cc=0;cc<4;cc++){
        float v = ac[cc];
        v = v > 0.f ? v : (__expf(v) - 1.f);
        oacc[r][cc] += 0.5f*v;
      }
    }
  }
#pragma unroll
  for(int r=0;r<4;r++){
    float4 o = make_float4(oacc[r][0], oacc[r][1], oacc[r][2], oacc[r][3]);
    *(float4*)(out + (size_t)(r0+rq*4+r)*C + cq*4) = o;
  }
}

extern "C" void kernel_launch(void* const* d_in, const int* in_sizes, int n_in,
                              void* d_out, int out_size, void* d_ws, size_t ws_size,
                              hipStream_t stream){
  const float* x   = (const float*)d_in[0];
  const float* adj = (const float*)d_in[1];
  const float* W0  = (const float*)d_in[2];
  const float* W1  = (const float*)d_in[3];
  const float* a   = (const float*)d_in[4];
  const float* g1  = (const float*)d_in[5];
  const float* b1  = (const float*)d_in[6];
  const float* g2  = (const float*)d_in[7];
  const float* b2  = (const float*)d_in[8];
  float* out = (float*)d_out;
  float* ws  = (float*)d_ws;

  float* xn   = ws;                          // 1,048,576 f
  float* h    = ws + 1048576;                // 2,097,152 f
  unsigned short* hB = (unsigned short*)(ws + 3145728); // 2,097,152 bf16 (1,048,576 f)
  float* hl   = ws + 4194304;                // 16,384 f
  float* hr   = ws + 4210688;                // 16,384 f
  float* invd = ws + 4227072;                // 16,384 f
  float* tmp  = ws + 4243456;                // 2,097,152 f
  float* pvp  = ws + 6340608;                // 16,777,216 f
  float* agg  = out + (size_t)N*C;

  k_ln1      <<<N/4, 256, 0, stream>>>(x, g1, b1, xn);
  k_gemm_xw  <<<dim3(N/32, 2), 256, 0, stream>>>(xn, W0, h);
  k_hB       <<<(2*N*C)/256, 256, 0, stream>>>(h, hB);
  k_hlr      <<<(2*N)/4, 256, 0, stream>>>(h, a, hl, hr);
  k_denom    <<<N/8, 512, 0, stream>>>(adj, hl, hr, invd);
  k_main     <<<dim3(128, 8), 256, 0, stream>>>(adj, hl, hr, invd, hB, agg, pvp);
  k_reduce_ln<<<(2*N)/4, 256, 0, stream>>>(pvp, invd, x, g2, b2, tmp);
  k_out      <<<N/32, 256, 0, stream>>>(tmp, W1, out);
}